// Round 1
// baseline (89.202 us; speedup 1.0000x reference)
//
#include <hip/hip_runtime.h>

// Problem constants (from reference)
#define BSZ 128
#define NPTS 16384
#define GL 48
#define GW 20
#define GH 18
#define VOX_PER_B (GL * GW * GH)       // 17280 floats = 67.5 KB
#define NTOT (BSZ * NPTS)              // 2,097,152 points
#define BLOCK 512
#define NWAVES (BLOCK / 64)            // 8
// R10: 4 blocks/batch at 512 threads -> 512 blocks = 2 blocks/CU (LDS 2x67.5=135KB
// <= 160KB). Two independent barrier domains per CU: one block computes while the
// other stages, attacking the stage->sync->compute serialization of the 1-block/CU
// layout. Voxel staging duplication (4x8.85MB nominal) is same-XCD -> L2-merged.
#define BLOCKS_PER_BATCH 4
#define NBLK (BSZ * BLOCKS_PER_BATCH)             // 512 blocks
#define PTS_PER_BLOCK (NPTS / BLOCKS_PER_BATCH)   // 4096
#define GROUP_PTS 4                                // consecutive points per thread-group
#define VEC4S (VOX_PER_B / 4)                      // 4320 float4s to stage
#define STAGE_FULL 8                               // 8*512 = 4096 full iterations
#define STAGE_TAIL (VEC4S - STAGE_FULL * BLOCK)    // 224-thread tail

__device__ __forceinline__ float clampf(float v, float lo, float hi) {
    return fminf(fmaxf(v, lo), hi);    // -> v_med3_f32
}

// One point's trilinear sample + huber, minimal-VALU form (see R6 notes):
// no divides, boundary cases folded into med3-clamped weights (exactly
// reproduces reference both-corners-clamped semantics; measured absmax 0.0),
// 8 corners = 4 ds_read2_b32 at constant offsets from 2 addresses.
__device__ __forceinline__ float point_loss(const float* __restrict__ vlds,
                                            float px, float py, float pz, float hg)
{
    const float xs = fmaf(px, 10.0f, 24.0f);           // (px+2.4)/0.1
    const float ys = fmaf(py, 10.0f, 10.0f);           // (py+1.0)/0.1
    const float zs = fmaf(pz, 10.0f, hg * 5.0f);       // (pz+hg/2)/0.1

    const float xbf = clampf(floorf(xs), 0.0f, (float)(GL - 2));
    const float ybf = clampf(floorf(ys), 0.0f, (float)(GW - 2));
    const float zbf = clampf(floorf(zs), 0.0f, (float)(GH - 2));

    const float tx = clampf(xs - xbf, 0.0f, 1.0f);
    const float ty = clampf(ys - ybf, 0.0f, 1.0f);
    const float tz = clampf(zs - zbf, 0.0f, 1.0f);
    const float sx = 1.0f - tx, sy = 1.0f - ty, sz = 1.0f - tz;

    const int xb = (int)xbf;
    const int yb = (int)ybf;
    const int zb = (int)zbf;

    const float* q  = vlds + (xb * (GW * GH) + yb * GH + zb);
    const float* q2 = q + (GW * GH);                   // x+1 plane

    const float c000 = q[0],   c001 = q[1];            // ds_read2 (0,1)
    const float c010 = q[GH],  c011 = q[GH + 1];       // ds_read2 (18,19)
    const float c100 = q2[0],  c101 = q2[1];
    const float c110 = q2[GH], c111 = q2[GH + 1];

    const float p00 = fmaf(tz, c001, sz * c000);
    const float p01 = fmaf(tz, c011, sz * c010);
    const float p10 = fmaf(tz, c101, sz * c100);
    const float p11 = fmaf(tz, c111, sz * c110);
    const float py0 = fmaf(ty, p01, sy * p00);
    const float py1 = fmaf(ty, p11, sy * p10);
    const float sdf = fmaf(tx, py1, sx * py0);

    const float ax = fabsf(sdf);
    return (ax < 1.0f) ? 0.5f * sdf * sdf : ax - 0.5f;
}

__global__ __launch_bounds__(BLOCK, 4) void trilinear_huber_lds_kernel(
    const float* __restrict__ voxels,   // [B, GL, GW, GH]
    const float* __restrict__ pts,      // [B, N, 3]
    const float* __restrict__ hgt,      // [B, N]
    float* __restrict__ out)            // [1]
{
    __shared__ float vlds[VOX_PER_B];   // 67.5 KB
    __shared__ float wsum[NWAVES];

    // Keep the 4 blocks of one batch on the same XCD (bid & 7 is the
    // round-robin XCD id): their duplicate voxel stages merge in that XCD's L2.
    const int bid     = blockIdx.x;
    const int xcd     = bid & 7;
    const int i       = bid >> 3;        // [0, 64)
    const int slot    = i & 15;
    const int quarter = i >> 4;          // [0, 4)
    const int b       = xcd * 16 + slot; // batch id [0, 128)
    const int tid     = threadIdx.x;
    const int lane    = tid & 63;
    const int wid     = tid >> 6;

    const int pbase = b * NPTS + quarter * PTS_PER_BLOCK;
    const int p0 = pbase + tid * GROUP_PTS;          // group 0 (4 consecutive pts)
    const int p1 = p0 + BLOCK * GROUP_PTS;           // group 1

    // Prefetch group-0 points so this HBM stream overlaps voxel staging.
    // Plain (cached) loads: R9 measured non-temporal loads as a 4 us
    // regression — L1/L2 line reuse within the 48 B/thread pattern matters.
    const float4* pp0 = (const float4*)(pts + 3 * (size_t)p0);   // 48 B aligned
    const float4 g0a = pp0[0], g0b = pp0[1], g0c = pp0[2];
    const float4 h0  = *(const float4*)(hgt + p0);

    // Stage batch voxel slice into LDS (fully-unrolled float4 copy).
    {
        const float4* vb4 = (const float4*)(voxels + (size_t)b * VOX_PER_B);
        float4* lds4 = (float4*)vlds;
        #pragma unroll
        for (int k = 0; k < STAGE_FULL; ++k)
            lds4[tid + k * BLOCK] = vb4[tid + k * BLOCK];
        if (tid < STAGE_TAIL)
            lds4[tid + STAGE_FULL * BLOCK] = vb4[tid + STAGE_FULL * BLOCK];
    }
    __syncthreads();

    // Issue group-1 prefetch before computing group 0.
    const float4* pp1 = (const float4*)(pts + 3 * (size_t)p1);
    const float4 g1a = pp1[0], g1b = pp1[1], g1c = pp1[2];
    const float4 h1  = *(const float4*)(hgt + p1);

    float acc = 0.0f;
    acc += point_loss(vlds, g0a.x, g0a.y, g0a.z, h0.x);
    acc += point_loss(vlds, g0a.w, g0b.x, g0b.y, h0.y);
    acc += point_loss(vlds, g0b.z, g0b.w, g0c.x, h0.z);
    acc += point_loss(vlds, g0c.y, g0c.z, g0c.w, h0.w);
    acc += point_loss(vlds, g1a.x, g1a.y, g1a.z, h1.x);
    acc += point_loss(vlds, g1a.w, g1b.x, g1b.y, h1.y);
    acc += point_loss(vlds, g1b.z, g1b.w, g1c.x, h1.z);
    acc += point_loss(vlds, g1c.y, g1c.z, g1c.w, h1.w);

    // wave-64 shuffle reduction, then block reduction, one atomic
    #pragma unroll
    for (int off = 32; off > 0; off >>= 1)
        acc += __shfl_down(acc, off, 64);

    if (lane == 0) wsum[wid] = acc;
    __syncthreads();

    if (tid == 0) {
        float bsum = 0.0f;
        #pragma unroll
        for (int w = 0; w < NWAVES; ++w) bsum += wsum[w];
        atomicAdd(out, bsum * (1.0f / (float)NTOT));
    }
}

extern "C" void kernel_launch(void* const* d_in, const int* in_sizes, int n_in,
                              void* d_out, int out_size, void* d_ws, size_t ws_size,
                              hipStream_t stream) {
    const float* voxels = (const float*)d_in[0];   // [B, 48, 20, 18]
    const float* pts    = (const float*)d_in[1];   // [B, N, 3]
    const float* hgt    = (const float*)d_in[2];   // [B, N]
    float* out = (float*)d_out;

    // d_out is poisoned to 0xAA before every timed replay — zero it in-graph.
    (void)hipMemsetAsync(out, 0, sizeof(float), stream);

    trilinear_huber_lds_kernel<<<NBLK, BLOCK, 0, stream>>>(voxels, pts, hgt, out);
}

// Round 2
// 88.760 us; speedup vs baseline: 1.0050x; 1.0050x over previous
//
#include <hip/hip_runtime.h>

// Problem constants (from reference)
#define BSZ 128
#define NPTS 16384
#define GL 48
#define GW 20
#define GH 18
#define VOX_PER_B (GL * GW * GH)       // 17280 floats = 67.5 KB
#define NTOT (BSZ * NPTS)              // 2,097,152 points
#define BLOCK 1024
#define NWAVES (BLOCK / 64)            // 16
// R11: back to the R0 shape — R10's 4-blocks/batch was a 3.3 us regression that
// matched its extra voxel staging traffic (+17.3 MB ~ +2.7 us), falsifying the
// phase-serialization theory. Kernel is near its HBM floor; keep dup at 2x
// (paired blocks are same-XCD so the dup largely merges in that XCD's L2).
#define BLOCKS_PER_BATCH 2
#define NBLK (BSZ * BLOCKS_PER_BATCH)             // 256 blocks -> 1 block/CU, 16 waves
#define PTS_PER_BLOCK (NPTS / BLOCKS_PER_BATCH)   // 8192
#define GROUP_PTS 4                                // consecutive points per thread-group
#define VEC4S (VOX_PER_B / 4)                      // 4320 float4s to stage
#define STAGE_FULL 4                               // 4*1024 = 4096 full iterations
#define STAGE_TAIL (VEC4S - STAGE_FULL * BLOCK)    // 224-thread tail

// Async global->LDS, 16 B per lane. LDS dest is wave-uniform base + lane*16;
// our staging layout lds4[tid + k*BLOCK] is exactly linear in tid, so this is
// the supported pattern (guide section 5, m97).
#define GLOAD_LDS16(gsrc, ldst)                                     \
    __builtin_amdgcn_global_load_lds(                               \
        (const __attribute__((address_space(1))) void*)(gsrc),      \
        (__attribute__((address_space(3))) void*)(ldst), 16, 0, 0)

__device__ __forceinline__ float clampf(float v, float lo, float hi) {
    return fminf(fmaxf(v, lo), hi);    // -> v_med3_f32
}

// One point's trilinear sample + huber, minimal-VALU form (see R6 notes):
// no divides, boundary cases folded into med3-clamped weights (exactly
// reproduces reference both-corners-clamped semantics; measured absmax 0.0),
// 8 corners = 4 ds_read2_b32 at constant offsets from 2 addresses.
__device__ __forceinline__ float point_loss(const float* __restrict__ vlds,
                                            float px, float py, float pz, float hg)
{
    const float xs = fmaf(px, 10.0f, 24.0f);           // (px+2.4)/0.1
    const float ys = fmaf(py, 10.0f, 10.0f);           // (py+1.0)/0.1
    const float zs = fmaf(pz, 10.0f, hg * 5.0f);       // (pz+hg/2)/0.1

    const float xbf = clampf(floorf(xs), 0.0f, (float)(GL - 2));
    const float ybf = clampf(floorf(ys), 0.0f, (float)(GW - 2));
    const float zbf = clampf(floorf(zs), 0.0f, (float)(GH - 2));

    const float tx = clampf(xs - xbf, 0.0f, 1.0f);
    const float ty = clampf(ys - ybf, 0.0f, 1.0f);
    const float tz = clampf(zs - zbf, 0.0f, 1.0f);
    const float sx = 1.0f - tx, sy = 1.0f - ty, sz = 1.0f - tz;

    const int xb = (int)xbf;
    const int yb = (int)ybf;
    const int zb = (int)zbf;

    const float* q  = vlds + (xb * (GW * GH) + yb * GH + zb);
    const float* q2 = q + (GW * GH);                   // x+1 plane

    const float c000 = q[0],   c001 = q[1];            // ds_read2 (0,1)
    const float c010 = q[GH],  c011 = q[GH + 1];       // ds_read2 (18,19)
    const float c100 = q2[0],  c101 = q2[1];
    const float c110 = q2[GH], c111 = q2[GH + 1];

    const float p00 = fmaf(tz, c001, sz * c000);
    const float p01 = fmaf(tz, c011, sz * c010);
    const float p10 = fmaf(tz, c101, sz * c100);
    const float p11 = fmaf(tz, c111, sz * c110);
    const float py0 = fmaf(ty, p01, sy * p00);
    const float py1 = fmaf(ty, p11, sy * p10);
    const float sdf = fmaf(tx, py1, sx * py0);

    const float ax = fabsf(sdf);
    return (ax < 1.0f) ? 0.5f * sdf * sdf : ax - 0.5f;
}

__global__ __launch_bounds__(BLOCK, 4) void trilinear_huber_lds_kernel(
    const float* __restrict__ voxels,   // [B, GL, GW, GH]
    const float* __restrict__ pts,      // [B, N, 3]
    const float* __restrict__ hgt,      // [B, N]
    float* __restrict__ out)            // [1]
{
    __shared__ float vlds[VOX_PER_B];   // 67.5 KB
    __shared__ float wsum[NWAVES];

    // Pair the two blocks of one batch mod 8 (same-XCD L2 merge of the
    // duplicate voxel stage; correctness does not depend on it).
    const int bid  = blockIdx.x;
    const int xcd  = bid & 7;
    const int slot = (bid >> 3) & 15;
    const int half = bid >> 7;          // [0, 2)
    const int b    = xcd * 16 + slot;   // batch id [0, 128)
    const int tid  = threadIdx.x;
    const int lane = tid & 63;
    const int wid  = tid >> 6;

    const int pbase = b * NPTS + half * PTS_PER_BLOCK;
    const int p0 = pbase + tid * GROUP_PTS;          // group 0 (4 consecutive pts)
    const int p1 = p0 + BLOCK * GROUP_PTS;           // group 1

    // Prefetch BOTH point groups before staging: with async staging freeing the
    // ~36 staging VGPRs, both 64-B groups fit in registers, so the entire pts/hgt
    // HBM latency hides under the voxel stage and the compute phase starts with
    // no VMEM dependency. Plain (cached) loads: R9 measured non-temporal as a
    // 4 us regression — line reuse within the 48 B/thread pattern matters.
    const float4* pp0 = (const float4*)(pts + 3 * (size_t)p0);   // 48 B aligned
    const float4 g0a = pp0[0], g0b = pp0[1], g0c = pp0[2];
    const float4 h0  = *(const float4*)(hgt + p0);
    const float4* pp1 = (const float4*)(pts + 3 * (size_t)p1);
    const float4 g1a = pp1[0], g1b = pp1[1], g1c = pp1[2];
    const float4 h1  = *(const float4*)(hgt + p1);

    // Stage batch voxel slice into LDS, async (no VGPR round-trip, no ds_write).
    // Layout is linear in tid -> matches global_load_lds's uniform-base+lane*16.
    {
        const float4* vb4 = (const float4*)(voxels + (size_t)b * VOX_PER_B);
        float4* lds4 = (float4*)vlds;
        #pragma unroll
        for (int k = 0; k < STAGE_FULL; ++k)
            GLOAD_LDS16(vb4 + tid + k * BLOCK, lds4 + tid + k * BLOCK);
        if (tid < STAGE_TAIL)
            GLOAD_LDS16(vb4 + tid + STAGE_FULL * BLOCK, lds4 + tid + STAGE_FULL * BLOCK);
    }
    __syncthreads();   // compiler emits vmcnt(0) drain covering the lds-loads

    float acc = 0.0f;
    acc += point_loss(vlds, g0a.x, g0a.y, g0a.z, h0.x);
    acc += point_loss(vlds, g0a.w, g0b.x, g0b.y, h0.y);
    acc += point_loss(vlds, g0b.z, g0b.w, g0c.x, h0.z);
    acc += point_loss(vlds, g0c.y, g0c.z, g0c.w, h0.w);
    acc += point_loss(vlds, g1a.x, g1a.y, g1a.z, h1.x);
    acc += point_loss(vlds, g1a.w, g1b.x, g1b.y, h1.y);
    acc += point_loss(vlds, g1b.z, g1b.w, g1c.x, h1.z);
    acc += point_loss(vlds, g1c.y, g1c.z, g1c.w, h1.w);

    // wave-64 shuffle reduction, then block reduction, one atomic
    #pragma unroll
    for (int off = 32; off > 0; off >>= 1)
        acc += __shfl_down(acc, off, 64);

    if (lane == 0) wsum[wid] = acc;
    __syncthreads();

    if (tid == 0) {
        float bsum = 0.0f;
        #pragma unroll
        for (int w = 0; w < NWAVES; ++w) bsum += wsum[w];
        atomicAdd(out, bsum * (1.0f / (float)NTOT));
    }
}

extern "C" void kernel_launch(void* const* d_in, const int* in_sizes, int n_in,
                              void* d_out, int out_size, void* d_ws, size_t ws_size,
                              hipStream_t stream) {
    const float* voxels = (const float*)d_in[0];   // [B, 48, 20, 18]
    const float* pts    = (const float*)d_in[1];   // [B, N, 3]
    const float* hgt    = (const float*)d_in[2];   // [B, N]
    float* out = (float*)d_out;

    // d_out is poisoned to 0xAA before every timed replay — zero it in-graph.
    (void)hipMemsetAsync(out, 0, sizeof(float), stream);

    trilinear_huber_lds_kernel<<<NBLK, BLOCK, 0, stream>>>(voxels, pts, hgt, out);
}

// Round 3
// 86.991 us; speedup vs baseline: 1.0254x; 1.0203x over previous
//
#include <hip/hip_runtime.h>

// Problem constants (from reference)
#define BSZ 128
#define NPTS 16384
#define GL 48
#define GW 20
#define GH 18
#define VOX_PER_B (GL * GW * GH)       // 17280 floats = 67.5 KB
#define NTOT (BSZ * NPTS)              // 2,097,152 points
#define BLOCK 1024
#define NWAVES (BLOCK / 64)            // 16
#define BLOCKS_PER_BATCH 2             // voxel HBM traffic = 2 x 8.85 MB by construction
#define NBLK (BSZ * BLOCKS_PER_BATCH)             // 256 blocks -> 1 block/CU, 16 waves
#define PTS_PER_BLOCK (NPTS / BLOCKS_PER_BATCH)   // 8192
#define GROUP_PTS 4                                // consecutive points per thread-group
#define VEC4S (VOX_PER_B / 4)                      // 4320 float4s to stage
#define STAGE_FULL 4                               // 4*1024 = 4096 full iterations
#define STAGE_TAIL (VEC4S - STAGE_FULL * BLOCK)    // 224-thread tail

// R12: R0 schedule (g0 prefetch -> stage -> barrier -> g1 prefetch -> compute)
// restored exactly — R2 proved hoisting g1 pre-barrier serializes 16.8 MB that
// otherwise overlaps compute (+2.9 us). Single change vs R0: staging goes
// through global_load_lds width-16 (async, no VGPR round-trip / ds_write).
// LDS dest is linear in tid -> wave-uniform base + lane*16, the supported form.
#define GLOAD_LDS16(gsrc, ldst)                                     \
    __builtin_amdgcn_global_load_lds(                               \
        (const __attribute__((address_space(1))) void*)(gsrc),      \
        (__attribute__((address_space(3))) void*)(ldst), 16, 0, 0)

__device__ __forceinline__ float clampf(float v, float lo, float hi) {
    return fminf(fmaxf(v, lo), hi);    // -> v_med3_f32
}

// One point's trilinear sample + huber, minimal-VALU form (see R6 notes):
// no divides, boundary cases folded into med3-clamped weights (exactly
// reproduces reference both-corners-clamped semantics; measured absmax 0.0),
// 8 corners = 4 ds_read2_b32 at constant offsets from 2 addresses.
__device__ __forceinline__ float point_loss(const float* __restrict__ vlds,
                                            float px, float py, float pz, float hg)
{
    const float xs = fmaf(px, 10.0f, 24.0f);           // (px+2.4)/0.1
    const float ys = fmaf(py, 10.0f, 10.0f);           // (py+1.0)/0.1
    const float zs = fmaf(pz, 10.0f, hg * 5.0f);       // (pz+hg/2)/0.1

    const float xbf = clampf(floorf(xs), 0.0f, (float)(GL - 2));
    const float ybf = clampf(floorf(ys), 0.0f, (float)(GW - 2));
    const float zbf = clampf(floorf(zs), 0.0f, (float)(GH - 2));

    const float tx = clampf(xs - xbf, 0.0f, 1.0f);
    const float ty = clampf(ys - ybf, 0.0f, 1.0f);
    const float tz = clampf(zs - zbf, 0.0f, 1.0f);
    const float sx = 1.0f - tx, sy = 1.0f - ty, sz = 1.0f - tz;

    const int xb = (int)xbf;
    const int yb = (int)ybf;
    const int zb = (int)zbf;

    const float* q  = vlds + (xb * (GW * GH) + yb * GH + zb);
    const float* q2 = q + (GW * GH);                   // x+1 plane

    const float c000 = q[0],   c001 = q[1];            // ds_read2 (0,1)
    const float c010 = q[GH],  c011 = q[GH + 1];       // ds_read2 (18,19)
    const float c100 = q2[0],  c101 = q2[1];
    const float c110 = q2[GH], c111 = q2[GH + 1];

    const float p00 = fmaf(tz, c001, sz * c000);
    const float p01 = fmaf(tz, c011, sz * c010);
    const float p10 = fmaf(tz, c101, sz * c100);
    const float p11 = fmaf(tz, c111, sz * c110);
    const float py0 = fmaf(ty, p01, sy * p00);
    const float py1 = fmaf(ty, p11, sy * p10);
    const float sdf = fmaf(tx, py1, sx * py0);

    const float ax = fabsf(sdf);
    return (ax < 1.0f) ? 0.5f * sdf * sdf : ax - 0.5f;
}

__global__ __launch_bounds__(BLOCK, 4) void trilinear_huber_lds_kernel(
    const float* __restrict__ voxels,   // [B, GL, GW, GH]
    const float* __restrict__ pts,      // [B, N, 3]
    const float* __restrict__ hgt,      // [B, N]
    float* __restrict__ out)            // [1]
{
    __shared__ float vlds[VOX_PER_B];   // 67.5 KB
    __shared__ float wsum[NWAVES];

    // Pair the two blocks of one batch mod 8 (same-XCD L2 merge of the
    // duplicate voxel stage; correctness does not depend on it).
    const int bid  = blockIdx.x;
    const int xcd  = bid & 7;
    const int slot = (bid >> 3) & 15;
    const int half = bid >> 7;          // [0, 2)
    const int b    = xcd * 16 + slot;   // batch id [0, 128)
    const int tid  = threadIdx.x;
    const int lane = tid & 63;
    const int wid  = tid >> 6;

    const int pbase = b * NPTS + half * PTS_PER_BLOCK;
    const int p0 = pbase + tid * GROUP_PTS;          // group 0 (4 consecutive pts)
    const int p1 = p0 + BLOCK * GROUP_PTS;           // group 1

    // Prefetch group-0 points so this HBM stream overlaps voxel staging.
    // Plain (cached) loads: R9 measured non-temporal loads as a 4 us
    // regression — L1/L2 line reuse within the 48 B/thread pattern matters.
    const float4* pp0 = (const float4*)(pts + 3 * (size_t)p0);   // 48 B aligned
    const float4 g0a = pp0[0], g0b = pp0[1], g0c = pp0[2];
    const float4 h0  = *(const float4*)(hgt + p0);

    // Stage batch voxel slice into LDS, async (no VGPR round-trip, no ds_write).
    {
        const float4* vb4 = (const float4*)(voxels + (size_t)b * VOX_PER_B);
        float4* lds4 = (float4*)vlds;
        #pragma unroll
        for (int k = 0; k < STAGE_FULL; ++k)
            GLOAD_LDS16(vb4 + tid + k * BLOCK, lds4 + tid + k * BLOCK);
        if (tid < STAGE_TAIL)
            GLOAD_LDS16(vb4 + tid + STAGE_FULL * BLOCK, lds4 + tid + STAGE_FULL * BLOCK);
    }
    __syncthreads();   // vmcnt(0) drain covers the lds-direct loads

    // Issue group-1 prefetch AFTER the barrier: overlaps group-0 compute
    // (R2 measured hoisting it pre-barrier as +2.9 us).
    const float4* pp1 = (const float4*)(pts + 3 * (size_t)p1);
    const float4 g1a = pp1[0], g1b = pp1[1], g1c = pp1[2];
    const float4 h1  = *(const float4*)(hgt + p1);

    float acc = 0.0f;
    acc += point_loss(vlds, g0a.x, g0a.y, g0a.z, h0.x);
    acc += point_loss(vlds, g0a.w, g0b.x, g0b.y, h0.y);
    acc += point_loss(vlds, g0b.z, g0b.w, g0c.x, h0.z);
    acc += point_loss(vlds, g0c.y, g0c.z, g0c.w, h0.w);
    acc += point_loss(vlds, g1a.x, g1a.y, g1a.z, h1.x);
    acc += point_loss(vlds, g1a.w, g1b.x, g1b.y, h1.y);
    acc += point_loss(vlds, g1b.z, g1b.w, g1c.x, h1.z);
    acc += point_loss(vlds, g1c.y, g1c.z, g1c.w, h1.w);

    // wave-64 shuffle reduction, then block reduction, one atomic
    #pragma unroll
    for (int off = 32; off > 0; off >>= 1)
        acc += __shfl_down(acc, off, 64);

    if (lane == 0) wsum[wid] = acc;
    __syncthreads();

    if (tid == 0) {
        float bsum = 0.0f;
        #pragma unroll
        for (int w = 0; w < NWAVES; ++w) bsum += wsum[w];
        atomicAdd(out, bsum * (1.0f / (float)NTOT));
    }
}

extern "C" void kernel_launch(void* const* d_in, const int* in_sizes, int n_in,
                              void* d_out, int out_size, void* d_ws, size_t ws_size,
                              hipStream_t stream) {
    const float* voxels = (const float*)d_in[0];   // [B, 48, 20, 18]
    const float* pts    = (const float*)d_in[1];   // [B, N, 3]
    const float* hgt    = (const float*)d_in[2];   // [B, N]
    float* out = (float*)d_out;

    // d_out is poisoned to 0xAA before every timed replay — zero it in-graph.
    (void)hipMemsetAsync(out, 0, sizeof(float), stream);

    trilinear_huber_lds_kernel<<<NBLK, BLOCK, 0, stream>>>(voxels, pts, hgt, out);
}

// Round 4
// 86.037 us; speedup vs baseline: 1.0368x; 1.0111x over previous
//
#include <hip/hip_runtime.h>

// Problem constants (from reference)
#define BSZ 128
#define NPTS 16384
#define GL 48
#define GW 20
#define GH 18
#define VOX_PER_B (GL * GW * GH)       // 17280 floats = 67.5 KB
#define NTOT (BSZ * NPTS)              // 2,097,152 points
#define BLOCK 1024
#define NWAVES (BLOCK / 64)            // 16
#define BLOCKS_PER_BATCH 2             // voxel HBM traffic = 2 x 8.85 MB by construction
#define NBLK (BSZ * BLOCKS_PER_BATCH)             // 256 blocks -> 1 block/CU, 16 waves
#define PTS_PER_BLOCK (NPTS / BLOCKS_PER_BATCH)   // 8192
#define GROUP_PTS 4                                // consecutive points per thread-group
#define VEC4S (VOX_PER_B / 4)                      // 4320 float4s to stage
#define STAGE_FULL 4                               // 4*1024 = 4096 full iterations
#define STAGE_TAIL (VEC4S - STAGE_FULL * BLOCK)    // 224-thread tail

// R13: restore the best-measured configuration (R0, 85.91 us) verbatim.
// Session A/B ledger, all single-variable deltas vs this baseline:
//   - 4 blocks/batch (R10/R1):      +3.3 us  (= +17.3 MB voxel re-stage traffic)
//   - g1 prefetch pre-barrier (R2): +2.9 us  (serializes 16.8 MB vs compute)
//   - async global_load_lds (R3):   +1.1 us  (stage phase is BW-bound, not
//     issue-bound; 16 waves/CU already hide the VGPR round-trip)
// Kernel ~9-10 us vs 8.1 us mandatory-HBM floor (pts 25.2 + hgt 8.4 +
// voxels 2x8.85 MB at 6.3 TB/s achievable). Remaining dur_us is harness-fixed
// (256 MiB ws poison fill ~43.5 us + reset dispatches).

__device__ __forceinline__ float clampf(float v, float lo, float hi) {
    return fminf(fmaxf(v, lo), hi);    // -> v_med3_f32
}

// One point's trilinear sample + huber, minimal-VALU form (see R6 notes):
// no divides, boundary cases folded into med3-clamped weights (exactly
// reproduces reference both-corners-clamped semantics; measured absmax 0.0),
// 8 corners = 4 ds_read2_b32 at constant offsets from 2 addresses.
__device__ __forceinline__ float point_loss(const float* __restrict__ vlds,
                                            float px, float py, float pz, float hg)
{
    const float xs = fmaf(px, 10.0f, 24.0f);           // (px+2.4)/0.1
    const float ys = fmaf(py, 10.0f, 10.0f);           // (py+1.0)/0.1
    const float zs = fmaf(pz, 10.0f, hg * 5.0f);       // (pz+hg/2)/0.1

    const float xbf = clampf(floorf(xs), 0.0f, (float)(GL - 2));
    const float ybf = clampf(floorf(ys), 0.0f, (float)(GW - 2));
    const float zbf = clampf(floorf(zs), 0.0f, (float)(GH - 2));

    const float tx = clampf(xs - xbf, 0.0f, 1.0f);
    const float ty = clampf(ys - ybf, 0.0f, 1.0f);
    const float tz = clampf(zs - zbf, 0.0f, 1.0f);
    const float sx = 1.0f - tx, sy = 1.0f - ty, sz = 1.0f - tz;

    const int xb = (int)xbf;
    const int yb = (int)ybf;
    const int zb = (int)zbf;

    const float* q  = vlds + (xb * (GW * GH) + yb * GH + zb);
    const float* q2 = q + (GW * GH);                   // x+1 plane

    const float c000 = q[0],   c001 = q[1];            // ds_read2 (0,1)
    const float c010 = q[GH],  c011 = q[GH + 1];       // ds_read2 (18,19)
    const float c100 = q2[0],  c101 = q2[1];
    const float c110 = q2[GH], c111 = q2[GH + 1];

    const float p00 = fmaf(tz, c001, sz * c000);
    const float p01 = fmaf(tz, c011, sz * c010);
    const float p10 = fmaf(tz, c101, sz * c100);
    const float p11 = fmaf(tz, c111, sz * c110);
    const float py0 = fmaf(ty, p01, sy * p00);
    const float py1 = fmaf(ty, p11, sy * p10);
    const float sdf = fmaf(tx, py1, sx * py0);

    const float ax = fabsf(sdf);
    return (ax < 1.0f) ? 0.5f * sdf * sdf : ax - 0.5f;
}

__global__ __launch_bounds__(BLOCK, 4) void trilinear_huber_lds_kernel(
    const float* __restrict__ voxels,   // [B, GL, GW, GH]
    const float* __restrict__ pts,      // [B, N, 3]
    const float* __restrict__ hgt,      // [B, N]
    float* __restrict__ out)            // [1]
{
    __shared__ float vlds[VOX_PER_B];   // 67.5 KB
    __shared__ float wsum[NWAVES];

    // Pair the two blocks of one batch mod 8 (possible same-XCD L2 bonus;
    // correctness/traffic do not depend on it).
    const int bid  = blockIdx.x;
    const int xcd  = bid & 7;
    const int slot = (bid >> 3) & 15;
    const int half = bid >> 7;          // [0, 2)
    const int b    = xcd * 16 + slot;   // batch id [0, 128)
    const int tid  = threadIdx.x;
    const int lane = tid & 63;
    const int wid  = tid >> 6;

    const int pbase = b * NPTS + half * PTS_PER_BLOCK;
    const int p0 = pbase + tid * GROUP_PTS;          // group 0 (4 consecutive pts)
    const int p1 = p0 + BLOCK * GROUP_PTS;           // group 1

    // Prefetch group-0 points so this HBM stream overlaps voxel staging.
    // Plain (cached) loads: R9 measured non-temporal loads as a 4 us
    // regression — L1/L2 line reuse within the 48 B/thread pattern matters.
    const float4* pp0 = (const float4*)(pts + 3 * (size_t)p0);   // 48 B aligned
    const float4 g0a = pp0[0], g0b = pp0[1], g0c = pp0[2];
    const float4 h0  = *(const float4*)(hgt + p0);

    // Stage batch voxel slice into LDS (fully-unrolled float4 copy).
    {
        const float4* vb4 = (const float4*)(voxels + (size_t)b * VOX_PER_B);
        float4* lds4 = (float4*)vlds;
        #pragma unroll
        for (int k = 0; k < STAGE_FULL; ++k)
            lds4[tid + k * BLOCK] = vb4[tid + k * BLOCK];
        if (tid < STAGE_TAIL)
            lds4[tid + STAGE_FULL * BLOCK] = vb4[tid + STAGE_FULL * BLOCK];
    }
    __syncthreads();

    // Issue group-1 prefetch AFTER the barrier: overlaps group-0 compute
    // (R2 measured hoisting it pre-barrier as +2.9 us).
    const float4* pp1 = (const float4*)(pts + 3 * (size_t)p1);
    const float4 g1a = pp1[0], g1b = pp1[1], g1c = pp1[2];
    const float4 h1  = *(const float4*)(hgt + p1);

    float acc = 0.0f;
    acc += point_loss(vlds, g0a.x, g0a.y, g0a.z, h0.x);
    acc += point_loss(vlds, g0a.w, g0b.x, g0b.y, h0.y);
    acc += point_loss(vlds, g0b.z, g0b.w, g0c.x, h0.z);
    acc += point_loss(vlds, g0c.y, g0c.z, g0c.w, h0.w);
    acc += point_loss(vlds, g1a.x, g1a.y, g1a.z, h1.x);
    acc += point_loss(vlds, g1a.w, g1b.x, g1b.y, h1.y);
    acc += point_loss(vlds, g1b.z, g1b.w, g1c.x, h1.z);
    acc += point_loss(vlds, g1c.y, g1c.z, g1c.w, h1.w);

    // wave-64 shuffle reduction, then block reduction, one atomic
    #pragma unroll
    for (int off = 32; off > 0; off >>= 1)
        acc += __shfl_down(acc, off, 64);

    if (lane == 0) wsum[wid] = acc;
    __syncthreads();

    if (tid == 0) {
        float bsum = 0.0f;
        #pragma unroll
        for (int w = 0; w < NWAVES; ++w) bsum += wsum[w];
        atomicAdd(out, bsum * (1.0f / (float)NTOT));
    }
}

extern "C" void kernel_launch(void* const* d_in, const int* in_sizes, int n_in,
                              void* d_out, int out_size, void* d_ws, size_t ws_size,
                              hipStream_t stream) {
    const float* voxels = (const float*)d_in[0];   // [B, 48, 20, 18]
    const float* pts    = (const float*)d_in[1];   // [B, N, 3]
    const float* hgt    = (const float*)d_in[2];   // [B, N]
    float* out = (float*)d_out;

    // d_out is poisoned to 0xAA before every timed replay — zero it in-graph.
    (void)hipMemsetAsync(out, 0, sizeof(float), stream);

    trilinear_huber_lds_kernel<<<NBLK, BLOCK, 0, stream>>>(voxels, pts, hgt, out);
}